// Round 9
// baseline (256.258 us; speedup 1.0000x reference)
//
#include <hip/hip_runtime.h>
#include <stdint.h>

#define NCLS 80
#define BATCH 8
#define NA 20460          // total anchors per image across 5 levels
#define TOPK 1000
#define MAXPER 100
#define POOL 256          // merge candidate pool (top-100 + tie slack)
#define IMG_WF 1280.0f
#define IMG_HF 768.0f
#define CLS_OFF 4096.0f
#define MAX_RATIO_ANCHOR 13.815510557964274f  // |log(1e-6)|
#define MAX_RATIO_BBOX   4.1351665567423557f  // |log(16/1000)|

// RN(a/b) > 0.5  <=>  a > b*(0.5 + 2^-25) as reals (0.5 mantissa even, tie->down).
// b has 24-bit mantissa, K2 has 25 -> product exact in f64; comparison exact.
#define K2_HALF_UP (0.5 + 0x1p-25)

__constant__ int   c_lvoff[6]  = {0, 15360, 19200, 20160, 20400, 20460};
__constant__ int   c_lvoff4[6] = {0, 3840, 4800, 5040, 5100, 5115};   // /4
__constant__ int   c_lw[5]    = {160, 80, 40, 20, 10};
__constant__ int   c_lh[5]    = {96, 48, 24, 12, 6};
__constant__ float c_ls[5]    = {8.f, 16.f, 32.f, 64.f, 128.f};

struct InPtrs {
  const float* cls[5];
  const float* bbox[5];
  const float* shp[5];
  const float* loc[5];
};

__device__ __forceinline__ float sigf(float x) { return 1.0f / (1.0f + expf(-x)); }

// ---- DPP wave64 reductions (VALU-only) ----
__device__ __forceinline__ int wave_red_sum_i32(int v) {
  int t;
  t = __builtin_amdgcn_update_dpp(0, v, 0x111, 0xf, 0xf, false); v += t;
  t = __builtin_amdgcn_update_dpp(0, v, 0x112, 0xf, 0xf, false); v += t;
  t = __builtin_amdgcn_update_dpp(0, v, 0x114, 0xf, 0xf, false); v += t;
  t = __builtin_amdgcn_update_dpp(0, v, 0x118, 0xf, 0xf, false); v += t;
  t = __builtin_amdgcn_update_dpp(0, v, 0x142, 0xf, 0xf, false); v += t;
  t = __builtin_amdgcn_update_dpp(0, v, 0x143, 0xf, 0xf, false); v += t;
  return __builtin_amdgcn_readlane(v, 63);
}
// top-2 of the wave's values: merge over disjoint sets; the row_shr/bcast tree's
// lane-63 path covers each lane exactly once, so the pair reduction is exact.
__device__ __forceinline__ void wave_red_top2(unsigned m1, unsigned m2,
                                              unsigned& r1, unsigned& r2) {
#define T2STEP(ctrl) { \
    unsigned o1 = (unsigned)__builtin_amdgcn_update_dpp(0, (int)m1, ctrl, 0xf, 0xf, false); \
    unsigned o2 = (unsigned)__builtin_amdgcn_update_dpp(0, (int)m2, ctrl, 0xf, 0xf, false); \
    unsigned tm = min(m1, o1); \
    m1 = max(m1, o1); \
    m2 = max(tm, max(m2, o2)); }
  T2STEP(0x111) T2STEP(0x112) T2STEP(0x114) T2STEP(0x118) T2STEP(0x142) T2STEP(0x143)
#undef T2STEP
  r1 = (unsigned)__builtin_amdgcn_readlane((int)m1, 63);
  r2 = (unsigned)__builtin_amdgcn_readlane((int)m2, 63);
}

// ---------------- K1: per-anchor max score, float4 over 4 anchors/thread --------
__global__ __launch_bounds__(256) void k_maxscore(InPtrs P, float* maxscore) {
  int gid = blockIdx.x * 256 + threadIdx.x;
  if (gid >= BATCH * (NA / 4)) return;
  int b = gid / (NA / 4);
  int q = gid - b * (NA / 4);          // float4 index within batch (level-merged)
  int l = 0;
  while (q >= c_lvoff4[l + 1]) ++l;
  int hw = c_lh[l] * c_lw[l];
  int sp = (q - c_lvoff4[l]) * 4;
  const float4* cls = (const float4*)(P.cls[l] + (size_t)(b * NCLS) * hw + sp);
  int s4 = hw >> 2;                    // class stride in float4 units
  float4 m = cls[0];
  for (int c = 1; c < NCLS; ++c) {
    float4 v = cls[(size_t)c * s4];
    m.x = fmaxf(m.x, v.x); m.y = fmaxf(m.y, v.y);
    m.z = fmaxf(m.z, v.z); m.w = fmaxf(m.w, v.w);
  }
  float4 lo = *(const float4*)(P.loc[l] + (size_t)b * hw + sp);
  float4 r;
  r.x = (sigf(lo.x) >= 0.01f) ? sigf(sigf(m.x)) : 0.0f;  // monotone: max commutes
  r.y = (sigf(lo.y) >= 0.01f) ? sigf(sigf(m.y)) : 0.0f;
  r.z = (sigf(lo.z) >= 0.01f) ? sigf(sigf(m.z)) : 0.0f;
  r.w = (sigf(lo.w) >= 0.01f) ? sigf(sigf(m.w)) : 0.0f;
  ((float4*)maxscore)[(size_t)b * (NA / 4) + q] = r;
}

// ---------------- K2: exact top-1000 per batch, in top_k order ----------------
// 3-pass LDS histogram radix search for the boundary V (22-bit score range,
// 8/8/6 bits), then collect (>V arbitrary, ==V index-ascending) and assign
// final positions by rank-by-counting (broadcast LDS reads, no bitonic).
__global__ __launch_bounds__(1024) void k_select(const float* maxscore, int* sel) {
  int b = blockIdx.x;
  const unsigned int* ms = (const unsigned int*)(maxscore + (size_t)b * NA);
  int tid = threadIdx.x;
  int wv = tid >> 6;
  int lane = tid & 63;
  __shared__ int s_hist[256];
  __shared__ int s_pos;
  __shared__ int s_wtot[16];
  __shared__ unsigned long long s_keys[1024];

  unsigned v[20], u[20];
  #pragma unroll
  for (int k = 0; k < 20; ++k) {
    int i = tid + k * 1024;
    v[k] = (i < NA) ? ms[i] : 0u;
    u[k] = v[k] - 0x3F000000u;   // nonzero scores -> [1, 0x3C0000); zero wraps huge
  }

  // ---- pass 1: bucket = u >> 14 (values < 240) ----
  if (tid < 256) s_hist[tid] = 0;
  __syncthreads();
  #pragma unroll
  for (int k = 0; k < 20; ++k) {
    unsigned bkt = u[k] >> 14;
    if (bkt < 256u) atomicAdd(&s_hist[bkt], 1);
  }
  __syncthreads();
  int B1 = -1, S1 = 0;
  {
    int acc = 0;
    for (int bb = 255; bb >= 0; --bb) {       // uniform walk (broadcast reads)
      int h = s_hist[bb];
      if (acc + h >= TOPK) { B1 = bb; S1 = acc; break; }
      acc += h;
    }
  }
  unsigned V = 0u;
  if (B1 >= 0) {
    // ---- pass 2: among bucket1==B1, bucket = (u>>6)&0xFF ----
    __syncthreads();
    if (tid < 256) s_hist[tid] = 0;
    __syncthreads();
    #pragma unroll
    for (int k = 0; k < 20; ++k) {
      if ((u[k] >> 14) == (unsigned)B1) atomicAdd(&s_hist[(u[k] >> 6) & 0xFFu], 1);
    }
    __syncthreads();
    int need2 = TOPK - S1;
    int B2 = 0, S2 = 0;
    {
      int acc = 0;
      for (int bb = 255; bb >= 0; --bb) {
        int h = s_hist[bb];
        if (acc + h >= need2) { B2 = bb; S2 = acc; break; }
        acc += h;
      }
    }
    // ---- pass 3: among (B1,B2), bucket = u & 63 ----
    __syncthreads();
    if (tid < 64) s_hist[tid] = 0;
    __syncthreads();
    unsigned pfx = ((unsigned)B1 << 8) | (unsigned)B2;
    #pragma unroll
    for (int k = 0; k < 20; ++k) {
      if ((u[k] >> 6) == pfx) atomicAdd(&s_hist[u[k] & 63u], 1);
    }
    __syncthreads();
    int need3 = need2 - S2;
    int B3 = 0;
    {
      int acc = 0;
      for (int bb = 63; bb >= 0; --bb) {
        int h = s_hist[bb];
        if (acc + h >= need3) { B3 = bb; break; }
        acc += h;
      }
    }
    V = 0x3F000000u + (((unsigned)B1 << 14) | ((unsigned)B2 << 6) | (unsigned)B3);
  }
  // V = bit pattern of the 1000th-largest value (0 if fewer than 1000 nonzero)

  if (tid == 0) s_pos = 0;
  if (tid < 1024 - TOPK) s_keys[TOPK + tid] = 0ull;  // pad slots
  __syncthreads();
  #pragma unroll
  for (int k = 0; k < 20; ++k) {
    int i = tid + k * 1024;
    if (v[k] > V) {   // count(>V) < 1000 guaranteed
      int p = atomicAdd(&s_pos, 1);
      s_keys[p] = ((unsigned long long)v[k] << 32) |
                  (unsigned long long)(0xFFFFFFFFu - (unsigned)i);
    }
  }
  __syncthreads();
  int ngt = s_pos;
  int need = TOPK - ngt;  // >= 1; filled by ==V in ascending index order
  const int CH = (NA + 1023) / 1024;  // 20, contiguous chunks (L2-hot re-read)
  int i0 = tid * CH, i1 = min(i0 + CH, NA);
  int ceq = 0;
  for (int i = i0; i < i1; ++i) ceq += (ms[i] == V) ? 1 : 0;

  // exclusive prefix over 1024 threads: shfl intra-wave scan + wave offsets
  int incl = ceq;
  #pragma unroll
  for (int o = 1; o < 64; o <<= 1) {
    int uu = __shfl_up(incl, o, 64);
    if (lane >= o) incl += uu;
  }
  if (lane == 63) s_wtot[wv] = incl;   // wave total
  __syncthreads();
  int woff = 0;
  #pragma unroll
  for (int w = 0; w < 16; ++w) woff += (w < wv) ? s_wtot[w] : 0;
  int r = woff + incl - ceq;           // global exclusive prefix
  for (int i = i0; i < i1 && r < need; ++i) {
    if (ms[i] == V) {
      s_keys[ngt + r] = ((unsigned long long)V << 32) |
                        (unsigned long long)(0xFFFFFFFFu - (unsigned)i);
      ++r;
    }
  }
  __syncthreads();

  // rank-by-counting: keys unique (index embedded) -> ranks are a permutation.
  unsigned long long mykey = s_keys[tid];
  int rank = 0;
  #pragma unroll 8
  for (int s = 0; s < 1024; ++s) rank += (s_keys[s] > mykey) ? 1 : 0;
  if (mykey != 0ull && rank < TOPK) {
    sel[b * TOPK + rank] = (int)(0xFFFFFFFFu - (unsigned)(mykey & 0xFFFFFFFFull));
  }
}

// ---------------- K3: decode boxes + 80 class scores, one WAVE per row ----------
// sv is CLASS-MAJOR [b][class][row] (contiguous reads in k_nms). Writes are
// coalesced via an in-block LDS transpose: block = 4 consecutive rows of one
// batch (1000 % 4 == 0), stores one float4 (4 rows) per class.
__global__ __launch_bounds__(256) void k_gather(InPtrs P, const int* sel, float* boxes, float* sv) {
  int wvi = threadIdx.x >> 6;
  int lane = threadIdx.x & 63;
  int wid = blockIdx.x * 4 + wvi;      // grid is exactly BATCH*TOPK/4 blocks
  int b = wid / TOPK;
  int r = wid - b * TOPK;
  __shared__ float s_sc[4][NCLS];

  int a = sel[b * TOPK + r];       // uniform -> broadcast load
  int l = 0;
  while (a >= c_lvoff[l + 1]) ++l;
  int within = a - c_lvoff[l];
  int W = c_lw[l], H = c_lh[l];
  int y = within / W, x = within - y * W;
  int hw = H * W;
  int sp = within;
  float stride = c_ls[l];
  float px = (float)x * stride;
  float py = (float)y * stride;
  float pw = 4.0f * stride;

  // guided anchor from shape_pred (delta2bbox, dx=dy=0, no clip) — wave-uniform
  const float* shp = P.shp[l];
  float dws = shp[(b * 2 + 0) * hw + sp];
  float dhs = shp[(b * 2 + 1) * hw + sp];
  dws = fminf(fmaxf(dws, -MAX_RATIO_ANCHOR), MAX_RATIO_ANCHOR);
  dhs = fminf(fmaxf(dhs, -MAX_RATIO_ANCHOR), MAX_RATIO_ANCHOR);
  float gw = pw * expf(dws);
  float gh = pw * expf(dhs);
  float ax1 = px - 0.5f * gw, ax2 = px + 0.5f * gw;
  float ay1 = py - 0.5f * gh, ay2 = py + 0.5f * gh;

  // proposal from bbox_pred (delta2bbox with image clip)
  const float* bb = P.bbox[l];
  float dx = bb[(b * 4 + 0) * hw + sp];
  float dy = bb[(b * 4 + 1) * hw + sp];
  float dw = bb[(b * 4 + 2) * hw + sp];
  float dh = bb[(b * 4 + 3) * hw + sp];
  dw = fminf(fmaxf(dw, -MAX_RATIO_BBOX), MAX_RATIO_BBOX);
  dh = fminf(fmaxf(dh, -MAX_RATIO_BBOX), MAX_RATIO_BBOX);
  float px2 = (ax1 + ax2) * 0.5f, py2 = (ay1 + ay2) * 0.5f;
  float pw2 = ax2 - ax1, ph2 = ay2 - ay1;
  float gx = px2 + pw2 * dx, gy = py2 + ph2 * dy;
  float gw2 = pw2 * expf(dw), gh2 = ph2 * expf(dh);
  float x1 = fminf(fmaxf(gx - 0.5f * gw2, 0.0f), IMG_WF);
  float x2 = fminf(fmaxf(gx + 0.5f * gw2, 0.0f), IMG_WF);
  float y1 = fminf(fmaxf(gy - 0.5f * gh2, 0.0f), IMG_HF);
  float y2 = fminf(fmaxf(gy + 0.5f * gh2, 0.0f), IMG_HF);
  if (lane == 0) {
    float4 st; st.x = x1; st.y = y1; st.z = x2; st.w = y2;
    ((float4*)boxes)[b * TOPK + r] = st;
  }

  // scores -> LDS (lane = class; lanes handle c and c+64)
  const float* cls = P.cls[l];
  float sl = sigf(P.loc[l][b * hw + sp]);
  bool mask = (sl >= 0.01f);
  int base = (b * NCLS) * hw + sp;
  for (int c = lane; c < NCLS; c += 64) {
    float vv = 0.0f;
    if (mask) {
      float s2 = sigf(sigf(cls[base + c * hw]));
      vv = (s2 > 0.05f) ? s2 : 0.0f;   // SCORE_THR (strict >)
    }
    s_sc[wvi][c] = vv;
  }
  __syncthreads();
  // transpose-write: thread t<80 writes class t's float4 (4 consecutive rows)
  int t = threadIdx.x;
  if (t < NCLS) {
    int r0 = (b == (blockIdx.x * 4) / TOPK) ? (blockIdx.x * 4 - b * TOPK) : 0;  // = row of wave 0
    float4 o; o.x = s_sc[0][t]; o.y = s_sc[1][t]; o.z = s_sc[2][t]; o.w = s_sc[3][t];
    *(float4*)(sv + ((size_t)(b * NCLS + t) * TOPK + r0)) = o;
  }
}

// ---------------- K4: per-(batch,class) greedy NMS, FOUR waves, TWO picks/round --
// Packed u32 key: live scores sig(sig(x)) in (0.5, 0.734) share float bits[31:22]
// == 0x0FC, so key = (score_low22 << 10) | (1023 - row). Live <=> key >= 1024.
// Per round extract top-2 (a1, a2); a2 is the next greedy pick iff IoU(a1,a2)
// <= 0.5 (exact f64 check). Suppression RN(inter/denom)>0.5 computed exactly
// in f64 (no division). Sticky streams: kc = -kept.
__global__ __launch_bounds__(256) void k_nms(const float* boxes, const float* sv,
                                             float* keptScore, int* keptRow, int* kc) {
  int bc = blockIdx.x;              // 0..639
  int b = bc / NCLS;
  int c = bc - b * NCLS;
  int tid = threadIdx.x;
  int wv = tid >> 6, lane = tid & 63;

  __shared__ float4 s_box[TOPK];            // 16 KB (offset coords)
  __shared__ float  s_ard[TOPK];            // 4 KB: |val| = area, sign = degenerate
  __shared__ unsigned long long s_p2[2][4]; // parity-buffered per-wave (top1,top2)

  float x1[4], y1[4], x2[4], y2[4], ar[4];
  unsigned key[4];
  float off = (float)c * CLS_OFF;   // exact in f32
  const float* svc = sv + (size_t)(b * NCLS + c) * TOPK;   // class-major: contiguous
  #pragma unroll
  for (int j = 0; j < 4; ++j) {
    int row = j * 256 + tid;
    if (row < TOPK) {
      float4 bo = ((const float4*)boxes)[b * TOPK + row];
      // reference computes IoU/areas on OFFSET coords (f32-rounded) — replicate
      float a = bo.x + off, d = bo.y + off, e = bo.z + off, f = bo.w + off;
      x1[j] = a; y1[j] = d; x2[j] = e; y2[j] = f;
      ar[j] = (e - a) * (f - d);
      unsigned bits = __float_as_uint(svc[row]);   // 0 or in [0x3F000001,0x3F3C0000)
      key[j] = ((bits & 0x3FFFFFu) << 10) | (1023u - (unsigned)row);
      // self-IoU = RN(ar / RN(ar+1e-6)); degenerate <=> !(selfiou > 0.5)
      float sden = ar[j] + 1e-6f;
      bool deg = !((double)ar[j] > (double)sden * K2_HALF_UP);
      float4 sb; sb.x = a; sb.y = d; sb.z = e; sb.w = f;
      s_box[row] = sb;
      s_ard[row] = __uint_as_float(__float_as_uint(ar[j]) | (deg ? 0x80000000u : 0u));
    } else {
      x1[j] = y1[j] = x2[j] = y2[j] = ar[j] = 0.0f;
      key[j] = 0u;
    }
  }
  __syncthreads();   // boxes visible

  int kept = 0;
  bool sticky = false;
  float* ks = keptScore + (size_t)(b * NCLS + c) * MAXPER;
  int*   kr = keptRow   + (size_t)(b * NCLS + c) * MAXPER;

  for (int round = 0; round < MAXPER; ++round) {
    int par = round & 1;
    // local top-2 of 4 keys, then wave top-2, then cross-wave combine
    unsigned hi1 = max(key[0], key[1]), lo1 = min(key[0], key[1]);
    unsigned hi2 = max(key[2], key[3]), lo2 = min(key[2], key[3]);
    unsigned m1 = max(hi1, hi2);
    unsigned m2 = max(min(hi1, hi2), max(lo1, lo2));
    unsigned w1, w2;
    wave_red_top2(m1, m2, w1, w2);
    if (lane == 0) s_p2[par][wv] = ((unsigned long long)w1 << 32) | w2;
    __syncthreads();                          // ONE barrier per round
    unsigned k0 = 0u, k1 = 0u;
    #pragma unroll
    for (int w = 0; w < 4; ++w) {
      unsigned long long pp = s_p2[par][w];
      unsigned p1 = (unsigned)(pp >> 32), p2 = (unsigned)pp;
      unsigned tm = min(k0, p1);
      k0 = max(k0, p1);
      k1 = max(tm, max(k1, p2));
    }
    if (k0 < 1024u) break;                    // no live entries
    // ---- pick a1 ----
    int brow1 = 1023 - (int)(k0 & 1023u);
    float bs1 = __uint_as_float(0x3F000000u | (k0 >> 10));
    float4 bb1 = s_box[brow1];
    unsigned au1 = __float_as_uint(s_ard[brow1]);
    bool deg1 = (au1 >> 31) != 0u;
    float ba1 = __uint_as_float(au1 & 0x7FFFFFFFu);
    if (tid == 0) { ks[kept] = bs1; kr[kept] = brow1; }
    kept++;
    if (deg1) { sticky = true; break; }       // repeats forever in the ref scan
    if (kept >= MAXPER) break;
    // ---- try pick a2 (pre-suppression 2nd max) ----
    bool do2 = false, deg2 = false;
    float4 bb2; float ba2 = 0.0f;
    if (k1 >= 1024u) {
      int brow2 = 1023 - (int)(k1 & 1023u);
      float bs2 = __uint_as_float(0x3F000000u | (k1 >> 10));
      bb2 = s_box[brow2];
      unsigned au2 = __float_as_uint(s_ard[brow2]);
      deg2 = (au2 >> 31) != 0u;
      ba2 = __uint_as_float(au2 & 0x7FFFFFFFu);
      // a2 is next pick iff not suppressed by a1 (exact ref arithmetic)
      float ltx = fmaxf(bb1.x, bb2.x), rbx = fminf(bb1.z, bb2.z);
      float lty = fmaxf(bb1.y, bb2.y), rby = fminf(bb1.w, bb2.w);
      float w_ = fmaxf(rbx - ltx, 0.0f), h_ = fmaxf(rby - lty, 0.0f);
      float inter = w_ * h_;
      float denom = ((ba1 + ba2) - inter) + 1e-6f;
      if (!((double)inter > (double)denom * K2_HALF_UP)) {
        do2 = true;
        if (tid == 0) { ks[kept] = bs2; kr[kept] = brow2; }
        kept++;
      }
    }
    if (do2 && deg2) { sticky = true; break; }
    // ---- suppression: each box vs a1 (and a2 if emitted); OR == sequential ----
    #pragma unroll
    for (int j = 0; j < 4; ++j) {
      {
        float ltx = fmaxf(bb1.x, x1[j]), rbx = fminf(bb1.z, x2[j]);
        float lty = fmaxf(bb1.y, y1[j]), rby = fminf(bb1.w, y2[j]);
        float w_ = fmaxf(rbx - ltx, 0.0f), h_ = fmaxf(rby - lty, 0.0f);
        float inter = w_ * h_;
        float denom = ((ba1 + ar[j]) - inter) + 1e-6f;
        if ((double)inter > (double)denom * K2_HALF_UP) key[j] = 0u;
      }
      if (do2) {
        float ltx = fmaxf(bb2.x, x1[j]), rbx = fminf(bb2.z, x2[j]);
        float lty = fmaxf(bb2.y, y1[j]), rby = fminf(bb2.w, y2[j]);
        float w_ = fmaxf(rbx - ltx, 0.0f), h_ = fmaxf(rby - lty, 0.0f);
        float inter = w_ * h_;
        float denom = ((ba2 + ar[j]) - inter) + 1e-6f;
        if ((double)inter > (double)denom * K2_HALF_UP) key[j] = 0u;
      }
    }
    if (kept >= MAXPER) break;
  }
  if (tid == 0) kc[b * NCLS + c] = sticky ? -kept : kept;
}

// ---------------- K5: sort-based merge -> top-100 (rank-by-count) ----------------
// Global sort of the stream union by (score desc, flat asc) == merge-by-max-head;
// sticky element repeats forever => truncate at first sticky, pad with it.
__global__ __launch_bounds__(256) void k_merge(const float* boxes, const float* keptScore,
                                               const int* keptRow, const int* kc, float* out) {
  int b = blockIdx.x;
  int tid = threadIdx.x;
  int wv = tid >> 6, lane = tid & 63;
  __shared__ int s_kc[NCLS];
  __shared__ int s_part[2][4];
  __shared__ int s_pos;
  __shared__ int s_sticky;
  __shared__ int s_navail;
  __shared__ unsigned long long s_pool[POOL];     // 2 KB
  __shared__ unsigned long long s_sorted[POOL];   // 2 KB

  for (int c = tid; c < NCLS; c += 256) s_kc[c] = kc[b * NCLS + c];
  if (tid == 0) { s_pos = 0; s_sticky = 0x7FFFFFFF; s_navail = 0; }
  for (int i = tid; i < POOL; i += 256) { s_pool[i] = 0ull; s_sorted[i] = 0ull; }
  __syncthreads();

  // load all stream scores into registers (coalesced; invalid -> 0)
  unsigned sc[32];
  #pragma unroll
  for (int s = 0; s < 32; ++s) {
    int i = tid + s * 256;
    unsigned vv = 0u;
    if (i < NCLS * MAXPER) {
      int c = i / MAXPER, k = i - c * MAXPER;
      int kcv = s_kc[c];
      int ka = (kcv < 0) ? -kcv : kcv;
      if (k < ka) vv = __float_as_uint(keptScore[(size_t)b * NCLS * MAXPER + i]);
    }
    sc[s] = vv;
  }

  int par = 0;
  auto countGE = [&](unsigned mid) -> int {
    int c = 0;
    #pragma unroll
    for (int s = 0; s < 32; ++s) c += (sc[s] >= mid) ? 1 : 0;
    c = wave_red_sum_i32(c);
    if (lane == 0) s_part[par][wv] = c;
    __syncthreads();
    int tot = s_part[par][0] + s_part[par][1] + s_part[par][2] + s_part[par][3];
    par ^= 1;
    return tot;
  };

  // all valid scores are sig(sig(x)) in (0.5, 0.734): bits in [0x3F000001, 0x3F3C0000)
  int T = countGE(0x3F000001u);        // total stream entries
  unsigned V = 0x3F000001u;            // pool threshold (all valid if T <= 100)
  if (T > MAXPER) {
    unsigned lo = 0x3F000001u, hi = 0x3F3C0000u;
    while (hi - lo > 1u) {
      unsigned mid = lo + (hi - lo) / 2u;
      if (countGE(mid) >= MAXPER) lo = mid; else hi = mid;
    }
    V = lo;   // count(>=V) >= 100, count(>V) < 100
  }

  // gather candidate pool (>= V). Overflow beyond POOL needs >=157 exact f32
  // score ties at the boundary — not reachable with continuous inputs.
  #pragma unroll
  for (int s = 0; s < 32; ++s) {
    if (sc[s] >= V) {
      int i = tid + s * 256;
      int c = i / MAXPER, k = i - c * MAXPER;
      int kcv = s_kc[c];
      int ka = (kcv < 0) ? -kcv : kcv;
      unsigned st = (kcv < 0 && k == ka - 1) ? 1u : 0u;
      unsigned row = (unsigned)keptRow[(size_t)b * NCLS * MAXPER + i];
      unsigned flat = row * 80u + (unsigned)c;
      int p = atomicAdd(&s_pos, 1);
      if (p < POOL)
        s_pool[p] = ((unsigned long long)sc[s] << 32) |
                    (unsigned long long)(0x7FFFFFFFu - ((flat << 1) | st));
    }
  }
  __syncthreads();

  // rank-by-count (keys unique via flat index; zeros excluded -> ranks contiguous)
  if (tid < POOL) {
    unsigned long long mykey = s_pool[tid];
    if (mykey != 0ull) {
      int rank = 0;
      #pragma unroll 8
      for (int s = 0; s < POOL; ++s) rank += (s_pool[s] > mykey) ? 1 : 0;
      s_sorted[rank] = mykey;
    }
  }
  __syncthreads();

  // first sticky position among the leading valid entries; valid count
  if (tid < MAXPER) {
    unsigned long long key = s_sorted[tid];
    if (key != 0ull) {
      atomicAdd(&s_navail, 1);
      if ((((unsigned)key) & 1u) == 0u) atomicMin(&s_sticky, tid);  // low bit 0 <=> sticky
    }
  }
  __syncthreads();
  int navail = s_navail;               // valid entries form a prefix
  int p = s_sticky;
  int n = (p < navail) ? MAXPER : navail;

  // output layout (flat f32): [B] ndet | [B,100,4] boxes | [B,100] scores | [B,100] cls
  if (tid == 0) out[b] = (float)n;
  const int OB = BATCH;                    // 8
  const int OP = OB + BATCH * MAXPER * 4;  // 3208
  const int OS = OP + BATCH * MAXPER;      // 4008
  if (tid < MAXPER) {
    int k = tid;
    float bx0 = 0.f, bx1 = 0.f, bx2 = 0.f, bx3 = 0.f, scf = 0.f, cf = -1.0f;
    if (k < n) {
      int idx = (k > p) ? p : k;           // p == INT_MAX when no sticky -> idx = k
      unsigned long long key = s_sorted[idx];
      unsigned flat = (0x7FFFFFFFu - (unsigned)key) >> 1;
      unsigned cls = flat % 80u;
      unsigned row = flat / 80u;
      float4 bo = ((const float4*)boxes)[b * TOPK + row];
      bx0 = bo.x; bx1 = bo.y; bx2 = bo.z; bx3 = bo.w;
      scf = __uint_as_float((unsigned)(key >> 32));
      cf = (float)cls;
    }
    float* po = out + OB + (size_t)(b * MAXPER + k) * 4;
    po[0] = bx0; po[1] = bx1; po[2] = bx2; po[3] = bx3;
    out[OP + b * MAXPER + k] = scf;
    out[OS + b * MAXPER + k] = cf;
  }
}

extern "C" void kernel_launch(void* const* d_in, const int* in_sizes, int n_in,
                              void* d_out, int out_size, void* d_ws, size_t ws_size,
                              hipStream_t stream) {
  InPtrs P;
  for (int l = 0; l < 5; ++l) {
    P.cls[l]  = (const float*)d_in[4 * l + 0];
    P.bbox[l] = (const float*)d_in[4 * l + 1];
    P.shp[l]  = (const float*)d_in[4 * l + 2];
    P.loc[l]  = (const float*)d_in[4 * l + 3];
  }
  float* maxscore  = (float*)d_ws;                          // B*NA
  int*   sel       = (int*)(maxscore + BATCH * NA);         // B*TOPK
  float* boxes     = (float*)(sel + BATCH * TOPK);          // B*TOPK*4 (16B aligned)
  float* sv        = boxes + BATCH * TOPK * 4;              // B*80*TOPK (class-major)
  float* keptScore = sv + BATCH * NCLS * TOPK;              // B*80*100
  int*   keptRow   = (int*)(keptScore + BATCH * NCLS * MAXPER);
  int*   kc        = keptRow + BATCH * NCLS * MAXPER;
  float* out = (float*)d_out;

  k_maxscore<<<(BATCH * (NA / 4) + 255) / 256, 256, 0, stream>>>(P, maxscore);
  k_select<<<BATCH, 1024, 0, stream>>>(maxscore, sel);
  k_gather<<<BATCH * TOPK / 4, 256, 0, stream>>>(P, sel, boxes, sv);
  k_nms<<<BATCH * NCLS, 256, 0, stream>>>(boxes, sv, keptScore, keptRow, kc);
  k_merge<<<BATCH, 256, 0, stream>>>(boxes, keptScore, keptRow, kc, out);
}

// Round 10
// 252.330 us; speedup vs baseline: 1.0156x; 1.0156x over previous
//
#include <hip/hip_runtime.h>
#include <stdint.h>

#define NCLS 80
#define BATCH 8
#define NA 20460          // total anchors per image across 5 levels
#define TOPK 1000
#define MAXPER 100
#define CAP 8             // capped per-class NMS depth (exact fixup via flags)
#define POOL 256          // merge candidate pool (top-100 + tie slack)
#define IMG_WF 1280.0f
#define IMG_HF 768.0f
#define CLS_OFF 4096.0f
#define MAX_RATIO_ANCHOR 13.815510557964274f  // |log(1e-6)|
#define MAX_RATIO_BBOX   4.1351665567423557f  // |log(16/1000)|

// RN(a/b) > 0.5  <=>  a > b*(0.5 + 2^-25) as reals (0.5 mantissa even, tie->down).
// b has 24-bit mantissa, K2 has 25 -> product exact in f64; comparison exact.
#define K2_HALF_UP (0.5 + 0x1p-25)

__constant__ int   c_lvoff[6]  = {0, 15360, 19200, 20160, 20400, 20460};
__constant__ int   c_lvoff4[6] = {0, 3840, 4800, 5040, 5100, 5115};   // /4
__constant__ int   c_lw[5]    = {160, 80, 40, 20, 10};
__constant__ int   c_lh[5]    = {96, 48, 24, 12, 6};
__constant__ float c_ls[5]    = {8.f, 16.f, 32.f, 64.f, 128.f};

struct InPtrs {
  const float* cls[5];
  const float* bbox[5];
  const float* shp[5];
  const float* loc[5];
};

__device__ __forceinline__ float sigf(float x) { return 1.0f / (1.0f + expf(-x)); }

// ---- DPP wave64 reductions (VALU-only) ----
__device__ __forceinline__ int wave_red_sum_i32(int v) {
  int t;
  t = __builtin_amdgcn_update_dpp(0, v, 0x111, 0xf, 0xf, false); v += t;
  t = __builtin_amdgcn_update_dpp(0, v, 0x112, 0xf, 0xf, false); v += t;
  t = __builtin_amdgcn_update_dpp(0, v, 0x114, 0xf, 0xf, false); v += t;
  t = __builtin_amdgcn_update_dpp(0, v, 0x118, 0xf, 0xf, false); v += t;
  t = __builtin_amdgcn_update_dpp(0, v, 0x142, 0xf, 0xf, false); v += t;
  t = __builtin_amdgcn_update_dpp(0, v, 0x143, 0xf, 0xf, false); v += t;
  return __builtin_amdgcn_readlane(v, 63);
}
// top-2 of the wave's values: merge over disjoint sets; the row_shr/bcast tree's
// lane-63 path covers each lane exactly once, so the pair reduction is exact.
__device__ __forceinline__ void wave_red_top2(unsigned m1, unsigned m2,
                                              unsigned& r1, unsigned& r2) {
#define T2STEP(ctrl) { \
    unsigned o1 = (unsigned)__builtin_amdgcn_update_dpp(0, (int)m1, ctrl, 0xf, 0xf, false); \
    unsigned o2 = (unsigned)__builtin_amdgcn_update_dpp(0, (int)m2, ctrl, 0xf, 0xf, false); \
    unsigned tm = min(m1, o1); \
    m1 = max(m1, o1); \
    m2 = max(tm, max(m2, o2)); }
  T2STEP(0x111) T2STEP(0x112) T2STEP(0x114) T2STEP(0x118) T2STEP(0x142) T2STEP(0x143)
#undef T2STEP
  r1 = (unsigned)__builtin_amdgcn_readlane((int)m1, 63);
  r2 = (unsigned)__builtin_amdgcn_readlane((int)m2, 63);
}

// ---------------- K1: per-anchor max score, float4 over 4 anchors/thread --------
__global__ __launch_bounds__(256) void k_maxscore(InPtrs P, float* maxscore) {
  int gid = blockIdx.x * 256 + threadIdx.x;
  if (gid >= BATCH * (NA / 4)) return;
  int b = gid / (NA / 4);
  int q = gid - b * (NA / 4);          // float4 index within batch (level-merged)
  int l = 0;
  while (q >= c_lvoff4[l + 1]) ++l;
  int hw = c_lh[l] * c_lw[l];
  int sp = (q - c_lvoff4[l]) * 4;
  const float4* cls = (const float4*)(P.cls[l] + (size_t)(b * NCLS) * hw + sp);
  int s4 = hw >> 2;                    // class stride in float4 units
  float4 m = cls[0];
  for (int c = 1; c < NCLS; ++c) {
    float4 v = cls[(size_t)c * s4];
    m.x = fmaxf(m.x, v.x); m.y = fmaxf(m.y, v.y);
    m.z = fmaxf(m.z, v.z); m.w = fmaxf(m.w, v.w);
  }
  float4 lo = *(const float4*)(P.loc[l] + (size_t)b * hw + sp);
  float4 r;
  r.x = (sigf(lo.x) >= 0.01f) ? sigf(sigf(m.x)) : 0.0f;  // monotone: max commutes
  r.y = (sigf(lo.y) >= 0.01f) ? sigf(sigf(m.y)) : 0.0f;
  r.z = (sigf(lo.z) >= 0.01f) ? sigf(sigf(m.z)) : 0.0f;
  r.w = (sigf(lo.w) >= 0.01f) ? sigf(sigf(m.w)) : 0.0f;
  ((float4*)maxscore)[(size_t)b * (NA / 4) + q] = r;
}

// ---------------- K2: exact top-1000 per batch, in top_k order ----------------
// Register-held values; binary search on float bit patterns for the boundary V;
// collect (>V arbitrary, ==V index-ascending); final placement by rank-by-count.
__global__ __launch_bounds__(1024) void k_select(const float* maxscore, int* sel) {
  int b = blockIdx.x;
  const unsigned int* ms = (const unsigned int*)(maxscore + (size_t)b * NA);
  int tid = threadIdx.x;
  int wv = tid >> 6;
  int lane = tid & 63;
  __shared__ int s_part[2][16];       // parity double-buffered partials
  __shared__ int s_pos;
  __shared__ int s_wtot[16];
  __shared__ unsigned long long s_keys[1024];

  unsigned v[20];
  #pragma unroll
  for (int k = 0; k < 20; ++k) {
    int i = tid + k * 1024;
    v[k] = (i < NA) ? ms[i] : 0u;
  }

  int par = 0;
  auto countGE = [&](unsigned mid) -> int {
    int c = 0;
    #pragma unroll
    for (int k = 0; k < 20; ++k) c += (v[k] >= mid) ? 1 : 0;
    c = wave_red_sum_i32(c);
    if (lane == 0) s_part[par][wv] = c;
    __syncthreads();
    int tot = 0;
    #pragma unroll
    for (int w = 0; w < 16; ++w) tot += s_part[par][w];
    par ^= 1;
    return tot;
  };

  // any nonzero score = sig(sig(x)) > 0.5 (bits >= 0x3F000001) and < 0.734375
  unsigned lo, hi;
  if (countGE(0x3F000001u) >= TOPK) { lo = 0x3F000001u; hi = 0x3F3C0000u; }
  else                              { lo = 0u;          hi = 1u; }       // V = 0
  while (hi - lo > 1u) {
    unsigned mid = lo + (hi - lo) / 2u;
    if (countGE(mid) >= TOPK) lo = mid; else hi = mid;
  }
  unsigned V = lo;  // bit pattern of the 1000th-largest value

  if (tid == 0) s_pos = 0;
  if (tid < 1024 - TOPK) s_keys[TOPK + tid] = 0ull;  // pad slots
  __syncthreads();
  #pragma unroll
  for (int k = 0; k < 20; ++k) {
    int i = tid + k * 1024;
    if (v[k] > V) {   // count(>V) < 1000 guaranteed
      int p = atomicAdd(&s_pos, 1);
      s_keys[p] = ((unsigned long long)v[k] << 32) |
                  (unsigned long long)(0xFFFFFFFFu - (unsigned)i);
    }
  }
  __syncthreads();
  int ngt = s_pos;
  int need = TOPK - ngt;  // >= 1; filled by ==V in ascending index order
  const int CH = (NA + 1023) / 1024;  // 20, contiguous chunks (L2-hot re-read)
  int i0 = tid * CH, i1 = min(i0 + CH, NA);
  int ceq = 0;
  for (int i = i0; i < i1; ++i) ceq += (ms[i] == V) ? 1 : 0;

  // exclusive prefix over 1024 threads: shfl intra-wave scan + wave offsets
  int incl = ceq;
  #pragma unroll
  for (int o = 1; o < 64; o <<= 1) {
    int uu = __shfl_up(incl, o, 64);
    if (lane >= o) incl += uu;
  }
  if (lane == 63) s_wtot[wv] = incl;   // wave total
  __syncthreads();
  int woff = 0;
  #pragma unroll
  for (int w = 0; w < 16; ++w) woff += (w < wv) ? s_wtot[w] : 0;
  int r = woff + incl - ceq;           // global exclusive prefix
  for (int i = i0; i < i1 && r < need; ++i) {
    if (ms[i] == V) {
      s_keys[ngt + r] = ((unsigned long long)V << 32) |
                        (unsigned long long)(0xFFFFFFFFu - (unsigned)i);
      ++r;
    }
  }
  __syncthreads();

  // rank-by-counting: keys unique (index embedded) -> ranks are a permutation.
  unsigned long long mykey = s_keys[tid];
  int rank = 0;
  #pragma unroll 8
  for (int s = 0; s < 1024; ++s) rank += (s_keys[s] > mykey) ? 1 : 0;
  if (mykey != 0ull && rank < TOPK) {
    sel[b * TOPK + rank] = (int)(0xFFFFFFFFu - (unsigned)(mykey & 0xFFFFFFFFull));
  }
}

// ---------------- K3: decode boxes + 80 class scores, one WAVE per row ----------
// sv is CLASS-MAJOR [b][class][row]; writes coalesced via in-block LDS transpose.
__global__ __launch_bounds__(256) void k_gather(InPtrs P, const int* sel, float* boxes, float* sv) {
  int wvi = threadIdx.x >> 6;
  int lane = threadIdx.x & 63;
  int wid = blockIdx.x * 4 + wvi;      // grid is exactly BATCH*TOPK/4 blocks
  int b = wid / TOPK;
  int r = wid - b * TOPK;
  __shared__ float s_sc[4][NCLS];

  int a = sel[b * TOPK + r];       // uniform -> broadcast load
  int l = 0;
  while (a >= c_lvoff[l + 1]) ++l;
  int within = a - c_lvoff[l];
  int W = c_lw[l], H = c_lh[l];
  int y = within / W, x = within - y * W;
  int hw = H * W;
  int sp = within;
  float stride = c_ls[l];
  float px = (float)x * stride;
  float py = (float)y * stride;
  float pw = 4.0f * stride;

  // guided anchor from shape_pred (delta2bbox, dx=dy=0, no clip) — wave-uniform
  const float* shp = P.shp[l];
  float dws = shp[(b * 2 + 0) * hw + sp];
  float dhs = shp[(b * 2 + 1) * hw + sp];
  dws = fminf(fmaxf(dws, -MAX_RATIO_ANCHOR), MAX_RATIO_ANCHOR);
  dhs = fminf(fmaxf(dhs, -MAX_RATIO_ANCHOR), MAX_RATIO_ANCHOR);
  float gw = pw * expf(dws);
  float gh = pw * expf(dhs);
  float ax1 = px - 0.5f * gw, ax2 = px + 0.5f * gw;
  float ay1 = py - 0.5f * gh, ay2 = py + 0.5f * gh;

  // proposal from bbox_pred (delta2bbox with image clip)
  const float* bb = P.bbox[l];
  float dx = bb[(b * 4 + 0) * hw + sp];
  float dy = bb[(b * 4 + 1) * hw + sp];
  float dw = bb[(b * 4 + 2) * hw + sp];
  float dh = bb[(b * 4 + 3) * hw + sp];
  dw = fminf(fmaxf(dw, -MAX_RATIO_BBOX), MAX_RATIO_BBOX);
  dh = fminf(fmaxf(dh, -MAX_RATIO_BBOX), MAX_RATIO_BBOX);
  float px2 = (ax1 + ax2) * 0.5f, py2 = (ay1 + ay2) * 0.5f;
  float pw2 = ax2 - ax1, ph2 = ay2 - ay1;
  float gx = px2 + pw2 * dx, gy = py2 + ph2 * dy;
  float gw2 = pw2 * expf(dw), gh2 = ph2 * expf(dh);
  float x1 = fminf(fmaxf(gx - 0.5f * gw2, 0.0f), IMG_WF);
  float x2 = fminf(fmaxf(gx + 0.5f * gw2, 0.0f), IMG_WF);
  float y1 = fminf(fmaxf(gy - 0.5f * gh2, 0.0f), IMG_HF);
  float y2 = fminf(fmaxf(gy + 0.5f * gh2, 0.0f), IMG_HF);
  if (lane == 0) {
    float4 st; st.x = x1; st.y = y1; st.z = x2; st.w = y2;
    ((float4*)boxes)[b * TOPK + r] = st;
  }

  // scores -> LDS (lane = class; lanes handle c and c+64)
  const float* cls = P.cls[l];
  float sl = sigf(P.loc[l][b * hw + sp]);
  bool mask = (sl >= 0.01f);
  int base = (b * NCLS) * hw + sp;
  for (int c = lane; c < NCLS; c += 64) {
    float vv = 0.0f;
    if (mask) {
      float s2 = sigf(sigf(cls[base + c * hw]));
      vv = (s2 > 0.05f) ? s2 : 0.0f;   // SCORE_THR (strict >)
    }
    s_sc[wvi][c] = vv;
  }
  __syncthreads();
  // transpose-write: thread t<80 writes class t's float4 (4 consecutive rows)
  int t = threadIdx.x;
  if (t < NCLS) {
    int r0 = blockIdx.x * 4 - b * TOPK;   // row of wave 0 (TOPK % 4 == 0)
    float4 o; o.x = s_sc[0][t]; o.y = s_sc[1][t]; o.z = s_sc[2][t]; o.w = s_sc[3][t];
    *(float4*)(sv + ((size_t)(b * NCLS + t) * TOPK + r0)) = o;
  }
}

// ---------------- K4: per-(batch,class) greedy NMS, FOUR waves, TWO picks/round --
// cap = max picks to emit (prefix of the full greedy stream — exact).
// flags != nullptr: only blocks with flags[bc] != 0 run (fixup pass).
// Packed u32 key: live scores sig(sig(x)) in (0.5, 0.734) share float bits[31:22]
// == 0x0FC, so key = (score_low22 << 10) | (1023 - row). Live <=> key >= 1024.
// Suppression RN(inter/denom)>0.5 computed exactly in f64. Sticky: kc = -kept.
__global__ __launch_bounds__(256) void k_nms(const float* boxes, const float* sv,
                                             float* keptScore, int* keptRow, int* kc,
                                             const int* flags, int cap) {
  int bc = blockIdx.x;              // 0..639
  if (flags && flags[bc] == 0) return;   // uniform early-exit (fixup pass)
  int b = bc / NCLS;
  int c = bc - b * NCLS;
  int tid = threadIdx.x;
  int wv = tid >> 6, lane = tid & 63;

  __shared__ float4 s_box[TOPK];            // 16 KB (offset coords)
  __shared__ float  s_ard[TOPK];            // 4 KB: |val| = area, sign = degenerate
  __shared__ unsigned long long s_p2[2][4]; // parity-buffered per-wave (top1,top2)

  float x1[4], y1[4], x2[4], y2[4], ar[4];
  unsigned key[4];
  float off = (float)c * CLS_OFF;   // exact in f32
  const float* svc = sv + (size_t)(b * NCLS + c) * TOPK;   // class-major: contiguous
  #pragma unroll
  for (int j = 0; j < 4; ++j) {
    int row = j * 256 + tid;
    if (row < TOPK) {
      float4 bo = ((const float4*)boxes)[b * TOPK + row];
      // reference computes IoU/areas on OFFSET coords (f32-rounded) — replicate
      float a = bo.x + off, d = bo.y + off, e = bo.z + off, f = bo.w + off;
      x1[j] = a; y1[j] = d; x2[j] = e; y2[j] = f;
      ar[j] = (e - a) * (f - d);
      unsigned bits = __float_as_uint(svc[row]);   // 0 or in [0x3F000001,0x3F3C0000)
      key[j] = ((bits & 0x3FFFFFu) << 10) | (1023u - (unsigned)row);
      // self-IoU = RN(ar / RN(ar+1e-6)); degenerate <=> !(selfiou > 0.5)
      float sden = ar[j] + 1e-6f;
      bool deg = !((double)ar[j] > (double)sden * K2_HALF_UP);
      float4 sb; sb.x = a; sb.y = d; sb.z = e; sb.w = f;
      s_box[row] = sb;
      s_ard[row] = __uint_as_float(__float_as_uint(ar[j]) | (deg ? 0x80000000u : 0u));
    } else {
      x1[j] = y1[j] = x2[j] = y2[j] = ar[j] = 0.0f;
      key[j] = 0u;
    }
  }
  __syncthreads();   // boxes visible

  int kept = 0;
  bool sticky = false;
  float* ks = keptScore + (size_t)(b * NCLS + c) * MAXPER;
  int*   kr = keptRow   + (size_t)(b * NCLS + c) * MAXPER;

  for (int round = 0; round < cap; ++round) {
    int par = round & 1;
    // local top-2 of 4 keys, then wave top-2, then cross-wave combine
    unsigned hi1 = max(key[0], key[1]), lo1 = min(key[0], key[1]);
    unsigned hi2 = max(key[2], key[3]), lo2 = min(key[2], key[3]);
    unsigned m1 = max(hi1, hi2);
    unsigned m2 = max(min(hi1, hi2), max(lo1, lo2));
    unsigned w1, w2;
    wave_red_top2(m1, m2, w1, w2);
    if (lane == 0) s_p2[par][wv] = ((unsigned long long)w1 << 32) | w2;
    __syncthreads();                          // ONE barrier per round
    unsigned k0 = 0u, k1 = 0u;
    #pragma unroll
    for (int w = 0; w < 4; ++w) {
      unsigned long long pp = s_p2[par][w];
      unsigned p1 = (unsigned)(pp >> 32), p2 = (unsigned)pp;
      unsigned tm = min(k0, p1);
      k0 = max(k0, p1);
      k1 = max(tm, max(k1, p2));
    }
    if (k0 < 1024u) break;                    // no live entries
    // ---- pick a1 ----
    int brow1 = 1023 - (int)(k0 & 1023u);
    float bs1 = __uint_as_float(0x3F000000u | (k0 >> 10));
    float4 bb1 = s_box[brow1];
    unsigned au1 = __float_as_uint(s_ard[brow1]);
    bool deg1 = (au1 >> 31) != 0u;
    float ba1 = __uint_as_float(au1 & 0x7FFFFFFFu);
    if (tid == 0) { ks[kept] = bs1; kr[kept] = brow1; }
    kept++;
    if (deg1) { sticky = true; break; }       // repeats forever in the ref scan
    if (kept >= cap) break;
    // ---- try pick a2 (pre-suppression 2nd max) ----
    bool do2 = false, deg2 = false;
    float4 bb2; float ba2 = 0.0f;
    if (k1 >= 1024u) {
      int brow2 = 1023 - (int)(k1 & 1023u);
      float bs2 = __uint_as_float(0x3F000000u | (k1 >> 10));
      bb2 = s_box[brow2];
      unsigned au2 = __float_as_uint(s_ard[brow2]);
      deg2 = (au2 >> 31) != 0u;
      ba2 = __uint_as_float(au2 & 0x7FFFFFFFu);
      // a2 is next pick iff not suppressed by a1 (exact ref arithmetic)
      float ltx = fmaxf(bb1.x, bb2.x), rbx = fminf(bb1.z, bb2.z);
      float lty = fmaxf(bb1.y, bb2.y), rby = fminf(bb1.w, bb2.w);
      float w_ = fmaxf(rbx - ltx, 0.0f), h_ = fmaxf(rby - lty, 0.0f);
      float inter = w_ * h_;
      float denom = ((ba1 + ba2) - inter) + 1e-6f;
      if (!((double)inter > (double)denom * K2_HALF_UP)) {
        do2 = true;
        if (tid == 0) { ks[kept] = bs2; kr[kept] = brow2; }
        kept++;
      }
    }
    if (do2 && deg2) { sticky = true; break; }
    // ---- suppression: each box vs a1 (and a2 if emitted); OR == sequential ----
    #pragma unroll
    for (int j = 0; j < 4; ++j) {
      {
        float ltx = fmaxf(bb1.x, x1[j]), rbx = fminf(bb1.z, x2[j]);
        float lty = fmaxf(bb1.y, y1[j]), rby = fminf(bb1.w, y2[j]);
        float w_ = fmaxf(rbx - ltx, 0.0f), h_ = fmaxf(rby - lty, 0.0f);
        float inter = w_ * h_;
        float denom = ((ba1 + ar[j]) - inter) + 1e-6f;
        if ((double)inter > (double)denom * K2_HALF_UP) key[j] = 0u;
      }
      if (do2) {
        float ltx = fmaxf(bb2.x, x1[j]), rbx = fminf(bb2.z, x2[j]);
        float lty = fmaxf(bb2.y, y1[j]), rby = fminf(bb2.w, y2[j]);
        float w_ = fmaxf(rbx - ltx, 0.0f), h_ = fmaxf(rby - lty, 0.0f);
        float inter = w_ * h_;
        float denom = ((ba2 + ar[j]) - inter) + 1e-6f;
        if ((double)inter > (double)denom * K2_HALF_UP) key[j] = 0u;
      }
    }
    if (kept >= cap) break;
  }
  if (tid == 0) kc[b * NCLS + c] = sticky ? -kept : kept;
}

// ---------------- K4b: fixup decision ----------------
// G = 100th-largest score over the capped union (per batch). A class needs the
// full re-run iff it is at cap, non-sticky, and its cap-th score >= G (non-strict
// to make score-tie boundaries safe). Sticky streams are complete. If fewer than
// 100 entries exist, G stays 0 -> all at-cap classes flagged (safe, rare).
__global__ __launch_bounds__(256) void k_cut(const float* keptScore, const int* kc, int* flags) {
  int b = blockIdx.x;
  int tid = threadIdx.x;
  __shared__ int s_abs[NCLS];
  __shared__ int s_neg[NCLS];
  __shared__ unsigned long long s_keys[NCLS * CAP];   // 640 keys, 5 KB
  __shared__ unsigned s_G;

  if (tid < NCLS) {
    int v = kc[b * NCLS + tid];
    s_abs[tid] = (v < 0) ? -v : v;
    s_neg[tid] = (v < 0) ? 1 : 0;
  }
  if (tid == 0) s_G = 0u;
  for (int e = tid; e < NCLS * CAP; e += 256) s_keys[e] = 0ull;
  __syncthreads();
  for (int e = tid; e < NCLS * CAP; e += 256) {
    int c = e / CAP, k = e - c * CAP;
    if (k < s_abs[c]) {
      unsigned sb = __float_as_uint(keptScore[(size_t)b * NCLS * MAXPER + c * MAXPER + k]);
      s_keys[e] = ((unsigned long long)sb << 32) | (unsigned)(NCLS * CAP - 1 - e);
    }
  }
  __syncthreads();
  // rank-by-count; the unique key at rank 99 defines G
  for (int e = tid; e < NCLS * CAP; e += 256) {
    unsigned long long mk = s_keys[e];
    if (mk != 0ull) {
      int rank = 0;
      for (int s = 0; s < NCLS * CAP; ++s) rank += (s_keys[s] > mk) ? 1 : 0;
      if (rank == MAXPER - 1) s_G = (unsigned)(mk >> 32);
    }
  }
  __syncthreads();
  unsigned G = s_G;
  if (tid < NCLS) {
    int f = 0;
    if (s_abs[tid] == CAP && !s_neg[tid]) {
      unsigned slast = __float_as_uint(
          keptScore[(size_t)b * NCLS * MAXPER + tid * MAXPER + (CAP - 1)]);
      if (slast >= G) f = 1;   // scores > 0.5: bit compare == float compare
    }
    flags[b * NCLS + tid] = f;
  }
}

// ---------------- K5: sort-based merge -> top-100 (rank-by-count) ----------------
// Global sort of the stream union by (score desc, flat asc) == merge-by-max-head;
// sticky element repeats forever => truncate at first sticky, pad with it.
__global__ __launch_bounds__(256) void k_merge(const float* boxes, const float* keptScore,
                                               const int* keptRow, const int* kc, float* out) {
  int b = blockIdx.x;
  int tid = threadIdx.x;
  int wv = tid >> 6, lane = tid & 63;
  __shared__ int s_kc[NCLS];
  __shared__ int s_part[2][4];
  __shared__ int s_pos;
  __shared__ int s_sticky;
  __shared__ int s_navail;
  __shared__ unsigned long long s_pool[POOL];     // 2 KB
  __shared__ unsigned long long s_sorted[POOL];   // 2 KB

  for (int c = tid; c < NCLS; c += 256) s_kc[c] = kc[b * NCLS + c];
  if (tid == 0) { s_pos = 0; s_sticky = 0x7FFFFFFF; s_navail = 0; }
  for (int i = tid; i < POOL; i += 256) { s_pool[i] = 0ull; s_sorted[i] = 0ull; }
  __syncthreads();

  // load all stream scores into registers (coalesced; invalid -> 0)
  unsigned sc[32];
  #pragma unroll
  for (int s = 0; s < 32; ++s) {
    int i = tid + s * 256;
    unsigned vv = 0u;
    if (i < NCLS * MAXPER) {
      int c = i / MAXPER, k = i - c * MAXPER;
      int kcv = s_kc[c];
      int ka = (kcv < 0) ? -kcv : kcv;
      if (k < ka) vv = __float_as_uint(keptScore[(size_t)b * NCLS * MAXPER + i]);
    }
    sc[s] = vv;
  }

  int par = 0;
  auto countGE = [&](unsigned mid) -> int {
    int c = 0;
    #pragma unroll
    for (int s = 0; s < 32; ++s) c += (sc[s] >= mid) ? 1 : 0;
    c = wave_red_sum_i32(c);
    if (lane == 0) s_part[par][wv] = c;
    __syncthreads();
    int tot = s_part[par][0] + s_part[par][1] + s_part[par][2] + s_part[par][3];
    par ^= 1;
    return tot;
  };

  // all valid scores are sig(sig(x)) in (0.5, 0.734): bits in [0x3F000001, 0x3F3C0000)
  int T = countGE(0x3F000001u);        // total stream entries
  unsigned V = 0x3F000001u;            // pool threshold (all valid if T <= 100)
  if (T > MAXPER) {
    unsigned lo = 0x3F000001u, hi = 0x3F3C0000u;
    while (hi - lo > 1u) {
      unsigned mid = lo + (hi - lo) / 2u;
      if (countGE(mid) >= MAXPER) lo = mid; else hi = mid;
    }
    V = lo;   // count(>=V) >= 100, count(>V) < 100
  }

  // gather candidate pool (>= V)
  #pragma unroll
  for (int s = 0; s < 32; ++s) {
    if (sc[s] >= V) {
      int i = tid + s * 256;
      int c = i / MAXPER, k = i - c * MAXPER;
      int kcv = s_kc[c];
      int ka = (kcv < 0) ? -kcv : kcv;
      unsigned st = (kcv < 0 && k == ka - 1) ? 1u : 0u;
      unsigned row = (unsigned)keptRow[(size_t)b * NCLS * MAXPER + i];
      unsigned flat = row * 80u + (unsigned)c;
      int p = atomicAdd(&s_pos, 1);
      if (p < POOL)
        s_pool[p] = ((unsigned long long)sc[s] << 32) |
                    (unsigned long long)(0x7FFFFFFFu - ((flat << 1) | st));
    }
  }
  __syncthreads();

  // rank-by-count (keys unique via flat index; zeros excluded -> ranks contiguous)
  if (tid < POOL) {
    unsigned long long mykey = s_pool[tid];
    if (mykey != 0ull) {
      int rank = 0;
      #pragma unroll 8
      for (int s = 0; s < POOL; ++s) rank += (s_pool[s] > mykey) ? 1 : 0;
      s_sorted[rank] = mykey;
    }
  }
  __syncthreads();

  // first sticky position among the leading valid entries; valid count
  if (tid < MAXPER) {
    unsigned long long key = s_sorted[tid];
    if (key != 0ull) {
      atomicAdd(&s_navail, 1);
      if ((((unsigned)key) & 1u) == 0u) atomicMin(&s_sticky, tid);  // low bit 0 <=> sticky
    }
  }
  __syncthreads();
  int navail = s_navail;               // valid entries form a prefix
  int p = s_sticky;
  int n = (p < navail) ? MAXPER : navail;

  // output layout (flat f32): [B] ndet | [B,100,4] boxes | [B,100] scores | [B,100] cls
  if (tid == 0) out[b] = (float)n;
  const int OB = BATCH;                    // 8
  const int OP = OB + BATCH * MAXPER * 4;  // 3208
  const int OS = OP + BATCH * MAXPER;      // 4008
  if (tid < MAXPER) {
    int k = tid;
    float bx0 = 0.f, bx1 = 0.f, bx2 = 0.f, bx3 = 0.f, scf = 0.f, cf = -1.0f;
    if (k < n) {
      int idx = (k > p) ? p : k;           // p == INT_MAX when no sticky -> idx = k
      unsigned long long key = s_sorted[idx];
      unsigned flat = (0x7FFFFFFFu - (unsigned)key) >> 1;
      unsigned cls = flat % 80u;
      unsigned row = flat / 80u;
      float4 bo = ((const float4*)boxes)[b * TOPK + row];
      bx0 = bo.x; bx1 = bo.y; bx2 = bo.z; bx3 = bo.w;
      scf = __uint_as_float((unsigned)(key >> 32));
      cf = (float)cls;
    }
    float* po = out + OB + (size_t)(b * MAXPER + k) * 4;
    po[0] = bx0; po[1] = bx1; po[2] = bx2; po[3] = bx3;
    out[OP + b * MAXPER + k] = scf;
    out[OS + b * MAXPER + k] = cf;
  }
}

extern "C" void kernel_launch(void* const* d_in, const int* in_sizes, int n_in,
                              void* d_out, int out_size, void* d_ws, size_t ws_size,
                              hipStream_t stream) {
  InPtrs P;
  for (int l = 0; l < 5; ++l) {
    P.cls[l]  = (const float*)d_in[4 * l + 0];
    P.bbox[l] = (const float*)d_in[4 * l + 1];
    P.shp[l]  = (const float*)d_in[4 * l + 2];
    P.loc[l]  = (const float*)d_in[4 * l + 3];
  }
  float* maxscore  = (float*)d_ws;                          // B*NA
  int*   sel       = (int*)(maxscore + BATCH * NA);         // B*TOPK
  float* boxes     = (float*)(sel + BATCH * TOPK);          // B*TOPK*4 (16B aligned)
  float* sv        = boxes + BATCH * TOPK * 4;              // B*80*TOPK (class-major)
  float* keptScore = sv + BATCH * NCLS * TOPK;              // B*80*100
  int*   keptRow   = (int*)(keptScore + BATCH * NCLS * MAXPER);
  int*   kc        = keptRow + BATCH * NCLS * MAXPER;
  int*   flags     = kc + BATCH * NCLS;
  float* out = (float*)d_out;

  k_maxscore<<<(BATCH * (NA / 4) + 255) / 256, 256, 0, stream>>>(P, maxscore);
  k_select<<<BATCH, 1024, 0, stream>>>(maxscore, sel);
  k_gather<<<BATCH * TOPK / 4, 256, 0, stream>>>(P, sel, boxes, sv);
  k_nms<<<BATCH * NCLS, 256, 0, stream>>>(boxes, sv, keptScore, keptRow, kc,
                                          (const int*)nullptr, CAP);
  k_cut<<<BATCH, 256, 0, stream>>>(keptScore, kc, flags);
  k_nms<<<BATCH * NCLS, 256, 0, stream>>>(boxes, sv, keptScore, keptRow, kc,
                                          flags, MAXPER);
  k_merge<<<BATCH, 256, 0, stream>>>(boxes, keptScore, keptRow, kc, out);
}

// Round 11
// 223.392 us; speedup vs baseline: 1.1471x; 1.1295x over previous
//
#include <hip/hip_runtime.h>
#include <stdint.h>

#define NCLS 80
#define BATCH 8
#define NA 20460          // total anchors per image across 5 levels
#define TOPK 1000
#define MAXPER 100
#define CAP 8             // capped per-class NMS depth (exact fixup via flags)
#define POOL 256          // merge candidate pool (top-100 + tie slack)
#define IMG_WF 1280.0f
#define IMG_HF 768.0f
#define CLS_OFF 4096.0f
#define MAX_RATIO_ANCHOR 13.815510557964274f  // |log(1e-6)|
#define MAX_RATIO_BBOX   4.1351665567423557f  // |log(16/1000)|

// RN(a/b) > 0.5  <=>  a > b*(0.5 + 2^-25) as reals (0.5 mantissa even, tie->down).
// b has 24-bit mantissa, K2 has 25 -> product exact in f64; comparison exact.
#define K2_HALF_UP (0.5 + 0x1p-25)

__constant__ int   c_lvoff[6]  = {0, 15360, 19200, 20160, 20400, 20460};
__constant__ int   c_lvoff4[6] = {0, 3840, 4800, 5040, 5100, 5115};   // /4
__constant__ int   c_lw[5]    = {160, 80, 40, 20, 10};
__constant__ int   c_lh[5]    = {96, 48, 24, 12, 6};
__constant__ float c_ls[5]    = {8.f, 16.f, 32.f, 64.f, 128.f};

struct InPtrs {
  const float* cls[5];
  const float* bbox[5];
  const float* shp[5];
  const float* loc[5];
};

__device__ __forceinline__ float sigf(float x) { return 1.0f / (1.0f + expf(-x)); }

// ---- DPP wave64 reductions (VALU-only) ----
__device__ __forceinline__ int wave_red_sum_i32(int v) {
  int t;
  t = __builtin_amdgcn_update_dpp(0, v, 0x111, 0xf, 0xf, false); v += t;
  t = __builtin_amdgcn_update_dpp(0, v, 0x112, 0xf, 0xf, false); v += t;
  t = __builtin_amdgcn_update_dpp(0, v, 0x114, 0xf, 0xf, false); v += t;
  t = __builtin_amdgcn_update_dpp(0, v, 0x118, 0xf, 0xf, false); v += t;
  t = __builtin_amdgcn_update_dpp(0, v, 0x142, 0xf, 0xf, false); v += t;
  t = __builtin_amdgcn_update_dpp(0, v, 0x143, 0xf, 0xf, false); v += t;
  return __builtin_amdgcn_readlane(v, 63);
}
// top-2 of the wave's values: merge over disjoint sets; the row_shr/bcast tree's
// lane-63 path covers each lane exactly once, so the pair reduction is exact.
__device__ __forceinline__ void wave_red_top2(unsigned m1, unsigned m2,
                                              unsigned& r1, unsigned& r2) {
#define T2STEP(ctrl) { \
    unsigned o1 = (unsigned)__builtin_amdgcn_update_dpp(0, (int)m1, ctrl, 0xf, 0xf, false); \
    unsigned o2 = (unsigned)__builtin_amdgcn_update_dpp(0, (int)m2, ctrl, 0xf, 0xf, false); \
    unsigned tm = min(m1, o1); \
    m1 = max(m1, o1); \
    m2 = max(tm, max(m2, o2)); }
  T2STEP(0x111) T2STEP(0x112) T2STEP(0x114) T2STEP(0x118) T2STEP(0x142) T2STEP(0x143)
#undef T2STEP
  r1 = (unsigned)__builtin_amdgcn_readlane((int)m1, 63);
  r2 = (unsigned)__builtin_amdgcn_readlane((int)m2, 63);
}

// ---------------- K1: per-anchor max score, float4 over 4 anchors/thread --------
__global__ __launch_bounds__(256) void k_maxscore(InPtrs P, float* maxscore) {
  int gid = blockIdx.x * 256 + threadIdx.x;
  if (gid >= BATCH * (NA / 4)) return;
  int b = gid / (NA / 4);
  int q = gid - b * (NA / 4);          // float4 index within batch (level-merged)
  int l = 0;
  while (q >= c_lvoff4[l + 1]) ++l;
  int hw = c_lh[l] * c_lw[l];
  int sp = (q - c_lvoff4[l]) * 4;
  const float4* cls = (const float4*)(P.cls[l] + (size_t)(b * NCLS) * hw + sp);
  int s4 = hw >> 2;                    // class stride in float4 units
  float4 m = cls[0];
  for (int c = 1; c < NCLS; ++c) {
    float4 v = cls[(size_t)c * s4];
    m.x = fmaxf(m.x, v.x); m.y = fmaxf(m.y, v.y);
    m.z = fmaxf(m.z, v.z); m.w = fmaxf(m.w, v.w);
  }
  float4 lo = *(const float4*)(P.loc[l] + (size_t)b * hw + sp);
  float4 r;
  r.x = (sigf(lo.x) >= 0.01f) ? sigf(sigf(m.x)) : 0.0f;  // monotone: max commutes
  r.y = (sigf(lo.y) >= 0.01f) ? sigf(sigf(m.y)) : 0.0f;
  r.z = (sigf(lo.z) >= 0.01f) ? sigf(sigf(m.z)) : 0.0f;
  r.w = (sigf(lo.w) >= 0.01f) ? sigf(sigf(m.w)) : 0.0f;
  ((float4*)maxscore)[(size_t)b * (NA / 4) + q] = r;
}

// ---------------- K2: exact top-1000 per batch, in top_k order ----------------
// Register-held values; parity-counter binary search for the boundary V;
// wave-aggregated collect; hybrid register bitonic (shfl intra-wave, 10
// double-buffered LDS cross-wave stages) for final (score desc, idx asc) order.
__global__ __launch_bounds__(1024) void k_select(const float* maxscore, int* sel) {
  int b = blockIdx.x;
  const unsigned int* ms = (const unsigned int*)(maxscore + (size_t)b * NA);
  int tid = threadIdx.x;
  int wv = tid >> 6;
  int lane = tid & 63;
  __shared__ int s_cnt[2];            // parity-buffered count
  __shared__ int s_pos;
  __shared__ int s_wtot[16];
  __shared__ unsigned long long s_A[1024];
  __shared__ unsigned long long s_B[1024];

  unsigned v[20];
  #pragma unroll
  for (int k = 0; k < 20; ++k) {
    int i = tid + k * 1024;
    v[k] = (i < NA) ? ms[i] : 0u;
  }
  if (tid == 0) { s_cnt[0] = 0; s_cnt[1] = 0; s_pos = 0; }
  __syncthreads();

  int par = 0;
  auto countGE = [&](unsigned mid) -> int {
    int c = 0;
    #pragma unroll
    for (int k = 0; k < 20; ++k) c += (v[k] >= mid) ? 1 : 0;
    c = wave_red_sum_i32(c);
    if (lane == 0) atomicAdd(&s_cnt[par], c);
    if (tid == 0) s_cnt[par ^ 1] = 0;   // pre-barrier: safe for next round
    __syncthreads();
    int tot = s_cnt[par];
    par ^= 1;
    return tot;
  };

  // any nonzero score = sig(sig(x)) > 0.5 (bits >= 0x3F000001) and < 0.734375
  unsigned lo, hi;
  if (countGE(0x3F000001u) >= TOPK) { lo = 0x3F000001u; hi = 0x3F3C0000u; }
  else                              { lo = 0u;          hi = 1u; }       // V = 0
  while (hi - lo > 1u) {
    unsigned mid = lo + (hi - lo) / 2u;
    if (countGE(mid) >= TOPK) lo = mid; else hi = mid;
  }
  unsigned V = lo;  // bit pattern of the 1000th-largest value

  if (tid < 1024 - TOPK) s_A[TOPK + tid] = 0ull;  // pad slots (sink in desc sort)
  // collect >V: wave-aggregated atomics (1 per wave per chunk, not 1 per item)
  #pragma unroll
  for (int k = 0; k < 20; ++k) {
    int i = tid + k * 1024;
    bool c = (v[k] > V);              // count(>V) < 1000 guaranteed
    unsigned long long bal = __ballot(c);
    int base = 0;
    if (lane == 0 && bal) base = atomicAdd(&s_pos, __popcll(bal));
    base = __shfl(base, 0, 64);
    if (c) {
      int off = __popcll(bal & ((1ull << lane) - 1ull));
      s_A[base + off] = ((unsigned long long)v[k] << 32) |
                        (unsigned long long)(0xFFFFFFFFu - (unsigned)i);
    }
  }
  __syncthreads();
  int ngt = s_pos;
  int need = TOPK - ngt;  // >= 1; filled by ==V in ascending index order
  const int CH = (NA + 1023) / 1024;  // 20, contiguous chunks (L2-hot re-read)
  int i0 = tid * CH, i1 = min(i0 + CH, NA);
  int ceq = 0;
  for (int i = i0; i < i1; ++i) ceq += (ms[i] == V) ? 1 : 0;

  // exclusive prefix over 1024 threads: shfl intra-wave scan + wave offsets
  int incl = ceq;
  #pragma unroll
  for (int o = 1; o < 64; o <<= 1) {
    int uu = __shfl_up(incl, o, 64);
    if (lane >= o) incl += uu;
  }
  if (lane == 63) s_wtot[wv] = incl;   // wave total
  __syncthreads();
  int woff = 0;
  #pragma unroll
  for (int w = 0; w < 16; ++w) woff += (w < wv) ? s_wtot[w] : 0;
  int r = woff + incl - ceq;           // global exclusive prefix
  for (int i = i0; i < i1 && r < need; ++i) {
    if (ms[i] == V) {
      s_A[ngt + r] = ((unsigned long long)V << 32) |
                     (unsigned long long)(0xFFFFFFFFu - (unsigned)i);
      ++r;
    }
  }
  __syncthreads();

  // hybrid bitonic sort, descending, one key/thread in registers.
  // strides < 64: shfl_xor (intra-wave, no barrier); strides >= 64: LDS
  // exchange, alternating buffers -> exactly ONE barrier per cross stage (10).
  unsigned long long key = s_A[tid];
  int tog = 0;   // 0 -> s_B first (s_A holds live data at entry)
  for (unsigned k = 2; k <= 1024; k <<= 1) {
    for (unsigned j = k >> 1; j > 0; j >>= 1) {
      unsigned long long other;
      if (j >= 64) {
        unsigned long long* cur = tog ? s_A : s_B;
        cur[tid] = key;
        __syncthreads();
        other = cur[tid ^ (int)j];
        tog ^= 1;
      } else {
        other = __shfl_xor(key, (int)j, 64);
      }
      bool takeMax = (((tid & (int)k) == 0) == ((tid & (int)j) == 0));
      unsigned long long mx = (key > other) ? key : other;
      unsigned long long mn = (key > other) ? other : key;
      key = takeMax ? mx : mn;
    }
  }
  if (tid < TOPK) {
    sel[b * TOPK + tid] = (int)(0xFFFFFFFFu - (unsigned)(key & 0xFFFFFFFFull));
  }
}

// ---------------- K3: decode boxes + 80 class scores, one WAVE per row ----------
// sv is CLASS-MAJOR [b][class][row]; writes coalesced via in-block LDS transpose.
__global__ __launch_bounds__(256) void k_gather(InPtrs P, const int* sel, float* boxes, float* sv) {
  int wvi = threadIdx.x >> 6;
  int lane = threadIdx.x & 63;
  int wid = blockIdx.x * 4 + wvi;      // grid is exactly BATCH*TOPK/4 blocks
  int b = wid / TOPK;
  int r = wid - b * TOPK;
  __shared__ float s_sc[4][NCLS];

  int a = sel[b * TOPK + r];       // uniform -> broadcast load
  int l = 0;
  while (a >= c_lvoff[l + 1]) ++l;
  int within = a - c_lvoff[l];
  int W = c_lw[l], H = c_lh[l];
  int y = within / W, x = within - y * W;
  int hw = H * W;
  int sp = within;
  float stride = c_ls[l];
  float px = (float)x * stride;
  float py = (float)y * stride;
  float pw = 4.0f * stride;

  // guided anchor from shape_pred (delta2bbox, dx=dy=0, no clip) — wave-uniform
  const float* shp = P.shp[l];
  float dws = shp[(b * 2 + 0) * hw + sp];
  float dhs = shp[(b * 2 + 1) * hw + sp];
  dws = fminf(fmaxf(dws, -MAX_RATIO_ANCHOR), MAX_RATIO_ANCHOR);
  dhs = fminf(fmaxf(dhs, -MAX_RATIO_ANCHOR), MAX_RATIO_ANCHOR);
  float gw = pw * expf(dws);
  float gh = pw * expf(dhs);
  float ax1 = px - 0.5f * gw, ax2 = px + 0.5f * gw;
  float ay1 = py - 0.5f * gh, ay2 = py + 0.5f * gh;

  // proposal from bbox_pred (delta2bbox with image clip)
  const float* bb = P.bbox[l];
  float dx = bb[(b * 4 + 0) * hw + sp];
  float dy = bb[(b * 4 + 1) * hw + sp];
  float dw = bb[(b * 4 + 2) * hw + sp];
  float dh = bb[(b * 4 + 3) * hw + sp];
  dw = fminf(fmaxf(dw, -MAX_RATIO_BBOX), MAX_RATIO_BBOX);
  dh = fminf(fmaxf(dh, -MAX_RATIO_BBOX), MAX_RATIO_BBOX);
  float px2 = (ax1 + ax2) * 0.5f, py2 = (ay1 + ay2) * 0.5f;
  float pw2 = ax2 - ax1, ph2 = ay2 - ay1;
  float gx = px2 + pw2 * dx, gy = py2 + ph2 * dy;
  float gw2 = pw2 * expf(dw), gh2 = ph2 * expf(dh);
  float x1 = fminf(fmaxf(gx - 0.5f * gw2, 0.0f), IMG_WF);
  float x2 = fminf(fmaxf(gx + 0.5f * gw2, 0.0f), IMG_WF);
  float y1 = fminf(fmaxf(gy - 0.5f * gh2, 0.0f), IMG_HF);
  float y2 = fminf(fmaxf(gy + 0.5f * gh2, 0.0f), IMG_HF);
  if (lane == 0) {
    float4 st; st.x = x1; st.y = y1; st.z = x2; st.w = y2;
    ((float4*)boxes)[b * TOPK + r] = st;
  }

  // scores -> LDS (lane = class; lanes handle c and c+64)
  const float* cls = P.cls[l];
  float sl = sigf(P.loc[l][b * hw + sp]);
  bool mask = (sl >= 0.01f);
  int base = (b * NCLS) * hw + sp;
  for (int c = lane; c < NCLS; c += 64) {
    float vv = 0.0f;
    if (mask) {
      float s2 = sigf(sigf(cls[base + c * hw]));
      vv = (s2 > 0.05f) ? s2 : 0.0f;   // SCORE_THR (strict >)
    }
    s_sc[wvi][c] = vv;
  }
  __syncthreads();
  // transpose-write: thread t<80 writes class t's float4 (4 consecutive rows)
  int t = threadIdx.x;
  if (t < NCLS) {
    int r0 = blockIdx.x * 4 - b * TOPK;   // row of wave 0 (TOPK % 4 == 0)
    float4 o; o.x = s_sc[0][t]; o.y = s_sc[1][t]; o.z = s_sc[2][t]; o.w = s_sc[3][t];
    *(float4*)(sv + ((size_t)(b * NCLS + t) * TOPK + r0)) = o;
  }
}

// ---------------- K4: per-(batch,class) greedy NMS, FOUR waves, TWO picks/round --
// cap = max picks to emit (prefix of the full greedy stream — exact).
// flags != nullptr: only blocks with flags[bc] != 0 run (fixup pass).
// Packed u32 key: live scores sig(sig(x)) in (0.5, 0.734) share float bits[31:22]
// == 0x0FC, so key = (score_low22 << 10) | (1023 - row). Live <=> key >= 1024.
// Suppression RN(inter/denom)>0.5 computed exactly in f64. Sticky: kc = -kept.
__global__ __launch_bounds__(256) void k_nms(const float* boxes, const float* sv,
                                             float* keptScore, int* keptRow, int* kc,
                                             const int* flags, int cap) {
  int bc = blockIdx.x;              // 0..639
  if (flags && flags[bc] == 0) return;   // uniform early-exit (fixup pass)
  int b = bc / NCLS;
  int c = bc - b * NCLS;
  int tid = threadIdx.x;
  int wv = tid >> 6, lane = tid & 63;

  __shared__ float4 s_box[TOPK];            // 16 KB (offset coords)
  __shared__ float  s_ard[TOPK];            // 4 KB: |val| = area, sign = degenerate
  __shared__ unsigned long long s_p2[2][4]; // parity-buffered per-wave (top1,top2)

  float x1[4], y1[4], x2[4], y2[4], ar[4];
  unsigned key[4];
  float off = (float)c * CLS_OFF;   // exact in f32
  const float* svc = sv + (size_t)(b * NCLS + c) * TOPK;   // class-major: contiguous
  #pragma unroll
  for (int j = 0; j < 4; ++j) {
    int row = j * 256 + tid;
    if (row < TOPK) {
      float4 bo = ((const float4*)boxes)[b * TOPK + row];
      // reference computes IoU/areas on OFFSET coords (f32-rounded) — replicate
      float a = bo.x + off, d = bo.y + off, e = bo.z + off, f = bo.w + off;
      x1[j] = a; y1[j] = d; x2[j] = e; y2[j] = f;
      ar[j] = (e - a) * (f - d);
      unsigned bits = __float_as_uint(svc[row]);   // 0 or in [0x3F000001,0x3F3C0000)
      key[j] = ((bits & 0x3FFFFFu) << 10) | (1023u - (unsigned)row);
      // self-IoU = RN(ar / RN(ar+1e-6)); degenerate <=> !(selfiou > 0.5)
      float sden = ar[j] + 1e-6f;
      bool deg = !((double)ar[j] > (double)sden * K2_HALF_UP);
      float4 sb; sb.x = a; sb.y = d; sb.z = e; sb.w = f;
      s_box[row] = sb;
      s_ard[row] = __uint_as_float(__float_as_uint(ar[j]) | (deg ? 0x80000000u : 0u));
    } else {
      x1[j] = y1[j] = x2[j] = y2[j] = ar[j] = 0.0f;
      key[j] = 0u;
    }
  }
  __syncthreads();   // boxes visible

  int kept = 0;
  bool sticky = false;
  float* ks = keptScore + (size_t)(b * NCLS + c) * MAXPER;
  int*   kr = keptRow   + (size_t)(b * NCLS + c) * MAXPER;

  for (int round = 0; round < cap; ++round) {
    int par = round & 1;
    // local top-2 of 4 keys, then wave top-2, then cross-wave combine
    unsigned hi1 = max(key[0], key[1]), lo1 = min(key[0], key[1]);
    unsigned hi2 = max(key[2], key[3]), lo2 = min(key[2], key[3]);
    unsigned m1 = max(hi1, hi2);
    unsigned m2 = max(min(hi1, hi2), max(lo1, lo2));
    unsigned w1, w2;
    wave_red_top2(m1, m2, w1, w2);
    if (lane == 0) s_p2[par][wv] = ((unsigned long long)w1 << 32) | w2;
    __syncthreads();                          // ONE barrier per round
    unsigned k0 = 0u, k1 = 0u;
    #pragma unroll
    for (int w = 0; w < 4; ++w) {
      unsigned long long pp = s_p2[par][w];
      unsigned p1 = (unsigned)(pp >> 32), p2 = (unsigned)pp;
      unsigned tm = min(k0, p1);
      k0 = max(k0, p1);
      k1 = max(tm, max(k1, p2));
    }
    if (k0 < 1024u) break;                    // no live entries
    // ---- pick a1 ----
    int brow1 = 1023 - (int)(k0 & 1023u);
    float bs1 = __uint_as_float(0x3F000000u | (k0 >> 10));
    float4 bb1 = s_box[brow1];
    unsigned au1 = __float_as_uint(s_ard[brow1]);
    bool deg1 = (au1 >> 31) != 0u;
    float ba1 = __uint_as_float(au1 & 0x7FFFFFFFu);
    if (tid == 0) { ks[kept] = bs1; kr[kept] = brow1; }
    kept++;
    if (deg1) { sticky = true; break; }       // repeats forever in the ref scan
    if (kept >= cap) break;
    // ---- try pick a2 (pre-suppression 2nd max) ----
    bool do2 = false, deg2 = false;
    float4 bb2; float ba2 = 0.0f;
    if (k1 >= 1024u) {
      int brow2 = 1023 - (int)(k1 & 1023u);
      float bs2 = __uint_as_float(0x3F000000u | (k1 >> 10));
      bb2 = s_box[brow2];
      unsigned au2 = __float_as_uint(s_ard[brow2]);
      deg2 = (au2 >> 31) != 0u;
      ba2 = __uint_as_float(au2 & 0x7FFFFFFFu);
      // a2 is next pick iff not suppressed by a1 (exact ref arithmetic)
      float ltx = fmaxf(bb1.x, bb2.x), rbx = fminf(bb1.z, bb2.z);
      float lty = fmaxf(bb1.y, bb2.y), rby = fminf(bb1.w, bb2.w);
      float w_ = fmaxf(rbx - ltx, 0.0f), h_ = fmaxf(rby - lty, 0.0f);
      float inter = w_ * h_;
      float denom = ((ba1 + ba2) - inter) + 1e-6f;
      if (!((double)inter > (double)denom * K2_HALF_UP)) {
        do2 = true;
        if (tid == 0) { ks[kept] = bs2; kr[kept] = brow2; }
        kept++;
      }
    }
    if (do2 && deg2) { sticky = true; break; }
    // ---- suppression: each box vs a1 (and a2 if emitted); OR == sequential ----
    #pragma unroll
    for (int j = 0; j < 4; ++j) {
      {
        float ltx = fmaxf(bb1.x, x1[j]), rbx = fminf(bb1.z, x2[j]);
        float lty = fmaxf(bb1.y, y1[j]), rby = fminf(bb1.w, y2[j]);
        float w_ = fmaxf(rbx - ltx, 0.0f), h_ = fmaxf(rby - lty, 0.0f);
        float inter = w_ * h_;
        float denom = ((ba1 + ar[j]) - inter) + 1e-6f;
        if ((double)inter > (double)denom * K2_HALF_UP) key[j] = 0u;
      }
      if (do2) {
        float ltx = fmaxf(bb2.x, x1[j]), rbx = fminf(bb2.z, x2[j]);
        float lty = fmaxf(bb2.y, y1[j]), rby = fminf(bb2.w, y2[j]);
        float w_ = fmaxf(rbx - ltx, 0.0f), h_ = fmaxf(rby - lty, 0.0f);
        float inter = w_ * h_;
        float denom = ((ba2 + ar[j]) - inter) + 1e-6f;
        if ((double)inter > (double)denom * K2_HALF_UP) key[j] = 0u;
      }
    }
    if (kept >= cap) break;
  }
  if (tid == 0) kc[b * NCLS + c] = sticky ? -kept : kept;
}

// ---------------- K4b: fixup decision ----------------
// G = 100th-largest score over the capped union (multiset order statistic ==
// rank-99 unique-key score), found by parity-counter binary search over
// register-held values. A class needs a full re-run iff at cap, non-sticky,
// and its cap-th score >= G. If fewer than 100 entries exist, G = 0 -> all
// at-cap classes flagged (safe, rare).
__global__ __launch_bounds__(256) void k_cut(const float* keptScore, const int* kc, int* flags) {
  int b = blockIdx.x;
  int tid = threadIdx.x;
  int lane = tid & 63;
  __shared__ int s_abs[NCLS];
  __shared__ int s_neg[NCLS];
  __shared__ int s_cnt[2];

  if (tid < NCLS) {
    int v = kc[b * NCLS + tid];
    s_abs[tid] = (v < 0) ? -v : v;
    s_neg[tid] = (v < 0) ? 1 : 0;
  }
  if (tid == 0) { s_cnt[0] = 0; s_cnt[1] = 0; }
  __syncthreads();

  unsigned vv[3] = {0u, 0u, 0u};
  #pragma unroll
  for (int t = 0; t < 3; ++t) {
    int e = tid + t * 256;
    if (e < NCLS * CAP) {
      int c = e / CAP, k = e - c * CAP;
      if (k < s_abs[c])
        vv[t] = __float_as_uint(keptScore[(size_t)b * NCLS * MAXPER + c * MAXPER + k]);
    }
  }

  int par = 0;
  auto countGE = [&](unsigned mid) -> int {
    int c = ((vv[0] >= mid) ? 1 : 0) + ((vv[1] >= mid) ? 1 : 0) + ((vv[2] >= mid) ? 1 : 0);
    c = wave_red_sum_i32(c);
    if (lane == 0) atomicAdd(&s_cnt[par], c);
    if (tid == 0) s_cnt[par ^ 1] = 0;
    __syncthreads();
    int tot = s_cnt[par];
    par ^= 1;
    return tot;
  };

  unsigned G = 0u;
  if (countGE(0x3F000001u) >= MAXPER) {
    unsigned lo = 0x3F000001u, hi = 0x3F3C0000u;
    while (hi - lo > 1u) {
      unsigned mid = lo + (hi - lo) / 2u;
      if (countGE(mid) >= MAXPER) lo = mid; else hi = mid;
    }
    G = lo;
  }
  if (tid < NCLS) {
    int f = 0;
    if (s_abs[tid] == CAP && !s_neg[tid]) {
      unsigned slast = __float_as_uint(
          keptScore[(size_t)b * NCLS * MAXPER + tid * MAXPER + (CAP - 1)]);
      if (slast >= G) f = 1;   // scores > 0.5: bit compare == float compare
    }
    flags[b * NCLS + tid] = f;
  }
}

// ---------------- K5: sort-based merge -> top-100 (rank-by-count) ----------------
// Global sort of the stream union by (score desc, flat asc) == merge-by-max-head;
// sticky element repeats forever => truncate at first sticky, pad with it.
__global__ __launch_bounds__(256) void k_merge(const float* boxes, const float* keptScore,
                                               const int* keptRow, const int* kc, float* out) {
  int b = blockIdx.x;
  int tid = threadIdx.x;
  int wv = tid >> 6, lane = tid & 63;
  __shared__ int s_kc[NCLS];
  __shared__ int s_part[2][4];
  __shared__ int s_pos;
  __shared__ int s_sticky;
  __shared__ int s_navail;
  __shared__ unsigned long long s_pool[POOL];     // 2 KB
  __shared__ unsigned long long s_sorted[POOL];   // 2 KB

  for (int c = tid; c < NCLS; c += 256) s_kc[c] = kc[b * NCLS + c];
  if (tid == 0) { s_pos = 0; s_sticky = 0x7FFFFFFF; s_navail = 0; }
  for (int i = tid; i < POOL; i += 256) { s_pool[i] = 0ull; s_sorted[i] = 0ull; }
  __syncthreads();

  // load all stream scores into registers (coalesced; invalid -> 0)
  unsigned sc[32];
  #pragma unroll
  for (int s = 0; s < 32; ++s) {
    int i = tid + s * 256;
    unsigned vv = 0u;
    if (i < NCLS * MAXPER) {
      int c = i / MAXPER, k = i - c * MAXPER;
      int kcv = s_kc[c];
      int ka = (kcv < 0) ? -kcv : kcv;
      if (k < ka) vv = __float_as_uint(keptScore[(size_t)b * NCLS * MAXPER + i]);
    }
    sc[s] = vv;
  }

  int par = 0;
  auto countGE = [&](unsigned mid) -> int {
    int c = 0;
    #pragma unroll
    for (int s = 0; s < 32; ++s) c += (sc[s] >= mid) ? 1 : 0;
    c = wave_red_sum_i32(c);
    if (lane == 0) s_part[par][wv] = c;
    __syncthreads();
    int tot = s_part[par][0] + s_part[par][1] + s_part[par][2] + s_part[par][3];
    par ^= 1;
    return tot;
  };

  // all valid scores are sig(sig(x)) in (0.5, 0.734): bits in [0x3F000001, 0x3F3C0000)
  int T = countGE(0x3F000001u);        // total stream entries
  unsigned V = 0x3F000001u;            // pool threshold (all valid if T <= 100)
  if (T > MAXPER) {
    unsigned lo = 0x3F000001u, hi = 0x3F3C0000u;
    while (hi - lo > 1u) {
      unsigned mid = lo + (hi - lo) / 2u;
      if (countGE(mid) >= MAXPER) lo = mid; else hi = mid;
    }
    V = lo;   // count(>=V) >= 100, count(>V) < 100
  }

  // gather candidate pool (>= V)
  #pragma unroll
  for (int s = 0; s < 32; ++s) {
    if (sc[s] >= V) {
      int i = tid + s * 256;
      int c = i / MAXPER, k = i - c * MAXPER;
      int kcv = s_kc[c];
      int ka = (kcv < 0) ? -kcv : kcv;
      unsigned st = (kcv < 0 && k == ka - 1) ? 1u : 0u;
      unsigned row = (unsigned)keptRow[(size_t)b * NCLS * MAXPER + i];
      unsigned flat = row * 80u + (unsigned)c;
      int p = atomicAdd(&s_pos, 1);
      if (p < POOL)
        s_pool[p] = ((unsigned long long)sc[s] << 32) |
                    (unsigned long long)(0x7FFFFFFFu - ((flat << 1) | st));
    }
  }
  __syncthreads();

  // rank-by-count (keys unique via flat index; zeros excluded -> ranks contiguous)
  if (tid < POOL) {
    unsigned long long mykey = s_pool[tid];
    if (mykey != 0ull) {
      int rank = 0;
      #pragma unroll 8
      for (int s = 0; s < POOL; ++s) rank += (s_pool[s] > mykey) ? 1 : 0;
      s_sorted[rank] = mykey;
    }
  }
  __syncthreads();

  // first sticky position among the leading valid entries; valid count
  if (tid < MAXPER) {
    unsigned long long key = s_sorted[tid];
    if (key != 0ull) {
      atomicAdd(&s_navail, 1);
      if ((((unsigned)key) & 1u) == 0u) atomicMin(&s_sticky, tid);  // low bit 0 <=> sticky
    }
  }
  __syncthreads();
  int navail = s_navail;               // valid entries form a prefix
  int p = s_sticky;
  int n = (p < navail) ? MAXPER : navail;

  // output layout (flat f32): [B] ndet | [B,100,4] boxes | [B,100] scores | [B,100] cls
  if (tid == 0) out[b] = (float)n;
  const int OB = BATCH;                    // 8
  const int OP = OB + BATCH * MAXPER * 4;  // 3208
  const int OS = OP + BATCH * MAXPER;      // 4008
  if (tid < MAXPER) {
    int k = tid;
    float bx0 = 0.f, bx1 = 0.f, bx2 = 0.f, bx3 = 0.f, scf = 0.f, cf = -1.0f;
    if (k < n) {
      int idx = (k > p) ? p : k;           // p == INT_MAX when no sticky -> idx = k
      unsigned long long key = s_sorted[idx];
      unsigned flat = (0x7FFFFFFFu - (unsigned)key) >> 1;
      unsigned cls = flat % 80u;
      unsigned row = flat / 80u;
      float4 bo = ((const float4*)boxes)[b * TOPK + row];
      bx0 = bo.x; bx1 = bo.y; bx2 = bo.z; bx3 = bo.w;
      scf = __uint_as_float((unsigned)(key >> 32));
      cf = (float)cls;
    }
    float* po = out + OB + (size_t)(b * MAXPER + k) * 4;
    po[0] = bx0; po[1] = bx1; po[2] = bx2; po[3] = bx3;
    out[OP + b * MAXPER + k] = scf;
    out[OS + b * MAXPER + k] = cf;
  }
}

extern "C" void kernel_launch(void* const* d_in, const int* in_sizes, int n_in,
                              void* d_out, int out_size, void* d_ws, size_t ws_size,
                              hipStream_t stream) {
  InPtrs P;
  for (int l = 0; l < 5; ++l) {
    P.cls[l]  = (const float*)d_in[4 * l + 0];
    P.bbox[l] = (const float*)d_in[4 * l + 1];
    P.shp[l]  = (const float*)d_in[4 * l + 2];
    P.loc[l]  = (const float*)d_in[4 * l + 3];
  }
  float* maxscore  = (float*)d_ws;                          // B*NA
  int*   sel       = (int*)(maxscore + BATCH * NA);         // B*TOPK
  float* boxes     = (float*)(sel + BATCH * TOPK);          // B*TOPK*4 (16B aligned)
  float* sv        = boxes + BATCH * TOPK * 4;              // B*80*TOPK (class-major)
  float* keptScore = sv + BATCH * NCLS * TOPK;              // B*80*100
  int*   keptRow   = (int*)(keptScore + BATCH * NCLS * MAXPER);
  int*   kc        = keptRow + BATCH * NCLS * MAXPER;
  int*   flags     = kc + BATCH * NCLS;
  float* out = (float*)d_out;

  k_maxscore<<<(BATCH * (NA / 4) + 255) / 256, 256, 0, stream>>>(P, maxscore);
  k_select<<<BATCH, 1024, 0, stream>>>(maxscore, sel);
  k_gather<<<BATCH * TOPK / 4, 256, 0, stream>>>(P, sel, boxes, sv);
  k_nms<<<BATCH * NCLS, 256, 0, stream>>>(boxes, sv, keptScore, keptRow, kc,
                                          (const int*)nullptr, CAP);
  k_cut<<<BATCH, 256, 0, stream>>>(keptScore, kc, flags);
  k_nms<<<BATCH * NCLS, 256, 0, stream>>>(boxes, sv, keptScore, keptRow, kc,
                                          flags, MAXPER);
  k_merge<<<BATCH, 256, 0, stream>>>(boxes, keptScore, keptRow, kc, out);
}